// Round 1
// baseline (2941.591 us; speedup 1.0000x reference)
//
#include <hip/hip_runtime.h>

#define N_NODES 100000
#define N_EDGES 1600000
#define HID 100
#define NG 128
#define NC 8

// degi[i]=1 accounts for the self-loop; also zero pooled sums / counts.
static __global__ void init_k(int* __restrict__ degi, float* __restrict__ pooled,
                              float* __restrict__ counts) {
  int i = blockIdx.x * blockDim.x + threadIdx.x;
  if (i < N_NODES) degi[i] = 1;
  if (i < NG * HID) pooled[i] = 0.0f;
  if (i < NG) counts[i] = 0.0f;
}

static __global__ void deg_k(const int* __restrict__ ei, int* __restrict__ degi) {
  int stride = gridDim.x * blockDim.x;
  for (int e = blockIdx.x * blockDim.x + threadIdx.x; e < N_EDGES; e += stride)
    atomicAdd(&degi[ei[N_EDGES + e]], 1);
}

static __global__ void dinv_k(const int* __restrict__ degi, float* __restrict__ dinv) {
  int i = blockIdx.x * blockDim.x + threadIdx.x;
  if (i < N_NODES) dinv[i] = 1.0f / sqrtf((float)degi[i]);
}

// Layer-1 "GEMM": h1[n,k] = x[n]*W1[k]; write hs = dinv*h1 to both A (self-loop
// init of the accumulator) and B (scatter source).
static __global__ void l1_k(const float* __restrict__ x, const float* __restrict__ W1,
                            const float* __restrict__ dinv, float* __restrict__ A,
                            float* __restrict__ B) {
  int i = blockIdx.x * blockDim.x + threadIdx.x;
  if (i >= N_NODES * HID) return;
  int n = i / HID;
  int k = i - n * HID;
  float v = x[n] * W1[k] * dinv[n];
  A[i] = v;
  B[i] = v;
}

// A[dst,:] += B[src,:] for every edge. Consecutive threads cover consecutive k
// of the same edge -> coalesced gather/atomics.
static __global__ void scatter_k(const int* __restrict__ ei, const float* __restrict__ B,
                                 float* __restrict__ A) {
  const int tot = N_EDGES * HID;
  int stride = gridDim.x * blockDim.x;
  for (int i = blockIdx.x * blockDim.x + threadIdx.x; i < tot; i += stride) {
    int e = i / HID;
    int k = i - e * HID;
    int s = ei[e];
    int d = ei[N_EDGES + e];
    atomicAdd(&A[d * HID + k], B[s * HID + k]);
  }
}

template <int RELU>
static __global__ void pw_k(float* __restrict__ A, const float* __restrict__ dinv,
                            const float* __restrict__ b) {
  int i = blockIdx.x * blockDim.x + threadIdx.x;
  if (i >= N_NODES * HID) return;
  int n = i / HID;
  int k = i - n * HID;
  float v = dinv[n] * A[i] + b[k];
  if (RELU) v = fmaxf(v, 0.0f);
  A[i] = v;
}

// Per-thread-per-node fp32 GEMM: h row (100 regs), W read via uniform (scalar)
// loads, acc chunked 25 at a time. Writes hs = dinv*(h@W) to Bout AND Aout
// (Aout == Ain is safe: each thread only touches its own row, and all reads
// complete into registers before the stores).
static __global__ __launch_bounds__(256) void gemm_k(const float* Ain,
    const float* __restrict__ W, const float* __restrict__ dinv,
    float* __restrict__ Bout, float* Aout) {
  int n = blockIdx.x * 256 + threadIdx.x;
  if (n >= N_NODES) return;
  float h[HID];
  const float4* hp = reinterpret_cast<const float4*>(Ain + (size_t)n * HID);
#pragma unroll
  for (int j = 0; j < HID / 4; ++j) {
    float4 v = hp[j];
    h[4 * j + 0] = v.x; h[4 * j + 1] = v.y; h[4 * j + 2] = v.z; h[4 * j + 3] = v.w;
  }
  const float di = dinv[n];
#pragma unroll 1
  for (int kc = 0; kc < 4; ++kc) {
    float acc[25];
#pragma unroll
    for (int k = 0; k < 25; ++k) acc[k] = 0.0f;
#pragma unroll
    for (int j = 0; j < HID; ++j) {
      const float hj = h[j];
      const float* wrow = W + j * HID + kc * 25;
#pragma unroll
      for (int k = 0; k < 25; ++k) acc[k] = fmaf(hj, wrow[k], acc[k]);
    }
    const int base = n * HID + kc * 25;
#pragma unroll
    for (int k = 0; k < 25; ++k) {
      float v = acc[k] * di;
      Bout[base + k] = v;
      Aout[base + k] = v;
    }
  }
}

// Layer-3 epilogue fused with mean-pool accumulation.
static __global__ void pool_k(const float* __restrict__ A, const float* __restrict__ dinv,
                              const float* __restrict__ b3, const int* __restrict__ batch,
                              float* __restrict__ pooled, float* __restrict__ counts) {
  int i = blockIdx.x * blockDim.x + threadIdx.x;
  if (i >= N_NODES * HID) return;
  int n = i / HID;
  int k = i - n * HID;
  float v = dinv[n] * A[i] + b3[k];
  int g = batch[n];
  atomicAdd(&pooled[g * HID + k], v);
  if (k == 0) atomicAdd(&counts[g], 1.0f);
}

static __global__ void head_k(const float* __restrict__ pooled, const float* __restrict__ counts,
                              const float* __restrict__ Wl, const float* __restrict__ bl,
                              float* __restrict__ out) {
  int i = blockIdx.x * blockDim.x + threadIdx.x;
  if (i >= NG * NC) return;
  int g = i / NC;
  int c = i - g * NC;
  float inv = 1.0f / fmaxf(counts[g], 1.0f);
  float acc = 0.0f;
#pragma unroll 4
  for (int j = 0; j < HID; ++j)
    acc = fmaf(pooled[g * HID + j] * inv, Wl[j * NC + c], acc);
  out[i] = acc + bl[c];
}

extern "C" void kernel_launch(void* const* d_in, const int* in_sizes, int n_in,
                              void* d_out, int out_size, void* d_ws, size_t ws_size,
                              hipStream_t stream) {
  const float* x    = (const float*)d_in[0];
  const int* ei     = (const int*)d_in[1];   // [2, E] flattened: src then dst
  const int* batch  = (const int*)d_in[2];
  const float* W1   = (const float*)d_in[3];
  const float* b1   = (const float*)d_in[4];
  const float* W2   = (const float*)d_in[5];
  const float* b2   = (const float*)d_in[6];
  const float* W3   = (const float*)d_in[7];
  const float* b3   = (const float*)d_in[8];
  const float* Wl   = (const float*)d_in[9];
  const float* bl   = (const float*)d_in[10];
  float* out = (float*)d_out;

  char* p = (char*)d_ws;
  auto alloc = [&](size_t bytes) {
    char* q = p;
    p += (bytes + 255) & ~(size_t)255;
    return q;
  };
  float* dinv   = (float*)alloc((size_t)N_NODES * 4);
  int*   degi   = (int*)alloc((size_t)N_NODES * 4);
  float* A      = (float*)alloc((size_t)N_NODES * HID * 4);
  float* B      = (float*)alloc((size_t)N_NODES * HID * 4);
  float* pooled = (float*)alloc((size_t)NG * HID * 4);
  float* counts = (float*)alloc((size_t)NG * 4);

  const int T = 256;
  int gN  = (N_NODES + T - 1) / T;
  int gNH = (N_NODES * HID + T - 1) / T;

  init_k<<<gN, T, 0, stream>>>(degi, pooled, counts);
  deg_k<<<2048, T, 0, stream>>>(ei, degi);
  dinv_k<<<gN, T, 0, stream>>>(degi, dinv);

  // layer 1
  l1_k<<<gNH, T, 0, stream>>>(x, W1, dinv, A, B);
  scatter_k<<<16384, T, 0, stream>>>(ei, B, A);
  pw_k<1><<<gNH, T, 0, stream>>>(A, dinv, b1);

  // layer 2
  gemm_k<<<gN, T, 0, stream>>>(A, W2, dinv, B, A);
  scatter_k<<<16384, T, 0, stream>>>(ei, B, A);
  pw_k<1><<<gNH, T, 0, stream>>>(A, dinv, b2);

  // layer 3
  gemm_k<<<gN, T, 0, stream>>>(A, W3, dinv, B, A);
  scatter_k<<<16384, T, 0, stream>>>(ei, B, A);
  pool_k<<<gNH, T, 0, stream>>>(A, dinv, b3, batch, pooled, counts);

  head_k<<<4, T, 0, stream>>>(pooled, counts, Wl, bl, out);
}

// Round 2
// 1763.315 us; speedup vs baseline: 1.6682x; 1.6682x over previous
//
#include <hip/hip_runtime.h>

#define N_NODES 100000
#define N_EDGES 1600000
#define HID 100
#define NG 128
#define NC 8

// degi[i]=1 accounts for the self-loop; zero fill counters and pooled sums.
static __global__ void init_k(int* __restrict__ degi, int* __restrict__ fill,
                              float* __restrict__ pooled) {
  int i = blockIdx.x * blockDim.x + threadIdx.x;
  if (i < N_NODES) { degi[i] = 1; fill[i] = 0; }
  if (i < NG * HID) pooled[i] = 0.0f;
}

static __global__ void deg_k(const int* __restrict__ ei, int* __restrict__ degi) {
  int stride = gridDim.x * blockDim.x;
  for (int e = blockIdx.x * blockDim.x + threadIdx.x; e < N_EDGES; e += stride)
    atomicAdd(&degi[ei[N_EDGES + e]], 1);
}

static __global__ void dinv_k(const int* __restrict__ degi, float* __restrict__ dinv) {
  int i = blockIdx.x * blockDim.x + threadIdx.x;
  if (i < N_NODES) dinv[i] = 1.0f / sqrtf((float)degi[i]);
}

// Exclusive prefix scan of in-edge counts (degi-1) -> rowptr. One block of 256
// threads, each owning a contiguous chunk; serial 256-scan by thread 0 (cheap).
#define SCAN_CHUNK 391  // ceil(100000/256)
static __global__ void scan_k(const int* __restrict__ degi, int* __restrict__ rowptr) {
  __shared__ int sums[256];
  int t = threadIdx.x;
  int lo = t * SCAN_CHUNK;
  int hi = min(lo + SCAN_CHUNK, N_NODES);
  int s = 0;
  for (int i = lo; i < hi; ++i) s += degi[i] - 1;
  sums[t] = s;
  __syncthreads();
  if (t == 0) {
    int run = 0;
    for (int i = 0; i < 256; ++i) { int v = sums[i]; sums[i] = run; run += v; }
  }
  __syncthreads();
  int run = sums[t];
  for (int i = lo; i < hi; ++i) { rowptr[i] = run; run += degi[i] - 1; }
  if (t == 255) rowptr[N_NODES] = run;  // == N_EDGES
}

static __global__ void fill_k(const int* __restrict__ ei, const int* __restrict__ rowptr,
                              int* __restrict__ fill, int* __restrict__ col) {
  int stride = gridDim.x * blockDim.x;
  for (int e = blockIdx.x * blockDim.x + threadIdx.x; e < N_EDGES; e += stride) {
    int d = ei[N_EDGES + e];
    int pos = rowptr[d] + atomicAdd(&fill[d], 1);
    col[pos] = ei[e];
  }
}

// Layer-1 "GEMM": hs[n,k] = x[n]*W1[k]*dinv[n] -> B (scatter source only).
static __global__ void l1_k(const float* __restrict__ x, const float* __restrict__ W1,
                            const float* __restrict__ dinv, float* __restrict__ B) {
  int i = blockIdx.x * blockDim.x + threadIdx.x;
  if (i >= N_NODES * HID) return;
  int n = i / HID;
  int k = i - n * HID;
  B[i] = x[n] * W1[k] * dinv[n];
}

// Pull-mode aggregation, fused epilogue: A[n,k] = act(dinv[n]*(B[n,k] +
// sum_{src->n} B[src,k]) + bias[k]). Two nodes per 256-thread block; each
// 128-thread slot is wave-uniform in n (no intra-wave divergence).
template <int RELU>
static __global__ __launch_bounds__(256) void agg_k(
    const int* __restrict__ rowptr, const int* __restrict__ col,
    const float* __restrict__ B, const float* __restrict__ dinv,
    const float* __restrict__ bias, float* __restrict__ A) {
  int slot = threadIdx.x >> 7;
  int k = threadIdx.x & 127;
  int n = blockIdx.x * 2 + slot;
  if (n >= N_NODES || k >= HID) return;
  float acc = B[n * HID + k];  // self-loop term
  int e0 = rowptr[n], e1 = rowptr[n + 1];
  int e = e0;
#pragma unroll 1
  for (; e + 2 <= e1; e += 2) {
    int s0 = col[e], s1 = col[e + 1];
    float v0 = B[s0 * HID + k];
    float v1 = B[s1 * HID + k];
    acc += v0;
    acc += v1;
  }
  if (e < e1) acc += B[col[e] * HID + k];
  float v = dinv[n] * acc + bias[k];
  if (RELU) v = fmaxf(v, 0.0f);
  A[n * HID + k] = v;
}

// Per-thread-per-node fp32 GEMM: h row (100 regs), W via uniform loads,
// acc chunked 25 at a time. Bout = dinv * (h @ W).
static __global__ __launch_bounds__(256) void gemm_k(const float* __restrict__ Ain,
    const float* __restrict__ W, const float* __restrict__ dinv,
    float* __restrict__ Bout) {
  int n = blockIdx.x * 256 + threadIdx.x;
  if (n >= N_NODES) return;
  float h[HID];
  const float4* hp = reinterpret_cast<const float4*>(Ain + (size_t)n * HID);
#pragma unroll
  for (int j = 0; j < HID / 4; ++j) {
    float4 v = hp[j];
    h[4 * j + 0] = v.x; h[4 * j + 1] = v.y; h[4 * j + 2] = v.z; h[4 * j + 3] = v.w;
  }
  const float di = dinv[n];
#pragma unroll 1
  for (int kc = 0; kc < 4; ++kc) {
    float acc[25];
#pragma unroll
    for (int k = 0; k < 25; ++k) acc[k] = 0.0f;
#pragma unroll
    for (int j = 0; j < HID; ++j) {
      const float hj = h[j];
      const float* wrow = W + j * HID + kc * 25;
#pragma unroll
      for (int k = 0; k < 25; ++k) acc[k] = fmaf(hj, wrow[k], acc[k]);
    }
    const int base = n * HID + kc * 25;
#pragma unroll
    for (int k = 0; k < 25; ++k) Bout[base + k] = acc[k] * di;
  }
}

static __device__ int lb(const int* __restrict__ a, int n, int v) {
  int lo = 0, hi = n;
  while (lo < hi) { int m = (lo + hi) >> 1; if (a[m] < v) lo = m + 1; else hi = m; }
  return lo;
}

// Sorted-segment mean pool: binary-search graph boundaries, 8 node-slices per
// graph, register partial sums, one atomic per (g, slice, k).
#define PSLICES 8
static __global__ void pool2_k(const float* __restrict__ A, const int* __restrict__ batch,
                               float* __restrict__ pooled, float* __restrict__ counts) {
  int g = blockIdx.x;
  int slice = blockIdx.y;
  int k = threadIdx.x;  // 128 threads
  int lo = lb(batch, N_NODES, g);
  int hi = lb(batch, N_NODES, g + 1);
  int cnt = hi - lo;
  if (slice == 0 && k == 0) counts[g] = (float)cnt;
  int per = (cnt + PSLICES - 1) / PSLICES;
  int s0 = lo + slice * per;
  int s1 = min(s0 + per, hi);
  if (k < HID && s1 > s0) {
    float s = 0.0f;
    for (int n = s0; n < s1; ++n) s += A[n * HID + k];
    atomicAdd(&pooled[g * HID + k], s);
  }
}

static __global__ void head_k(const float* __restrict__ pooled, const float* __restrict__ counts,
                              const float* __restrict__ Wl, const float* __restrict__ bl,
                              float* __restrict__ out) {
  int i = blockIdx.x * blockDim.x + threadIdx.x;
  if (i >= NG * NC) return;
  int g = i / NC;
  int c = i - g * NC;
  float inv = 1.0f / fmaxf(counts[g], 1.0f);
  float acc = 0.0f;
#pragma unroll 4
  for (int j = 0; j < HID; ++j)
    acc = fmaf(pooled[g * HID + j] * inv, Wl[j * NC + c], acc);
  out[i] = acc + bl[c];
}

extern "C" void kernel_launch(void* const* d_in, const int* in_sizes, int n_in,
                              void* d_out, int out_size, void* d_ws, size_t ws_size,
                              hipStream_t stream) {
  const float* x    = (const float*)d_in[0];
  const int* ei     = (const int*)d_in[1];   // [2, E] flattened: src then dst
  const int* batch  = (const int*)d_in[2];
  const float* W1   = (const float*)d_in[3];
  const float* b1   = (const float*)d_in[4];
  const float* W2   = (const float*)d_in[5];
  const float* b2   = (const float*)d_in[6];
  const float* W3   = (const float*)d_in[7];
  const float* b3   = (const float*)d_in[8];
  const float* Wl   = (const float*)d_in[9];
  const float* bl   = (const float*)d_in[10];
  float* out = (float*)d_out;

  char* p = (char*)d_ws;
  auto alloc = [&](size_t bytes) {
    char* q = p;
    p += (bytes + 255) & ~(size_t)255;
    return q;
  };
  float* dinv   = (float*)alloc((size_t)N_NODES * 4);
  int*   degi   = (int*)alloc((size_t)N_NODES * 4);
  int*   rowptr = (int*)alloc((size_t)(N_NODES + 1) * 4);
  int*   fill   = (int*)alloc((size_t)N_NODES * 4);
  int*   col    = (int*)alloc((size_t)N_EDGES * 4);
  float* A      = (float*)alloc((size_t)N_NODES * HID * 4);
  float* B      = (float*)alloc((size_t)N_NODES * HID * 4);
  float* pooled = (float*)alloc((size_t)NG * HID * 4);
  float* counts = (float*)alloc((size_t)NG * 4);

  const int T = 256;
  int gN  = (N_NODES + T - 1) / T;
  int gNH = (N_NODES * HID + T - 1) / T;
  int gAgg = (N_NODES + 1) / 2;

  init_k<<<gN, T, 0, stream>>>(degi, fill, pooled);
  deg_k<<<2048, T, 0, stream>>>(ei, degi);
  dinv_k<<<gN, T, 0, stream>>>(degi, dinv);
  scan_k<<<1, 256, 0, stream>>>(degi, rowptr);
  fill_k<<<2048, T, 0, stream>>>(ei, rowptr, fill, col);

  // layer 1
  l1_k<<<gNH, T, 0, stream>>>(x, W1, dinv, B);
  agg_k<1><<<gAgg, T, 0, stream>>>(rowptr, col, B, dinv, b1, A);

  // layer 2
  gemm_k<<<gN, T, 0, stream>>>(A, W2, dinv, B);
  agg_k<1><<<gAgg, T, 0, stream>>>(rowptr, col, B, dinv, b2, A);

  // layer 3
  gemm_k<<<gN, T, 0, stream>>>(A, W3, dinv, B);
  agg_k<0><<<gAgg, T, 0, stream>>>(rowptr, col, B, dinv, b3, A);

  pool2_k<<<dim3(NG, PSLICES), 128, 0, stream>>>(A, batch, pooled, counts);
  head_k<<<4, T, 0, stream>>>(pooled, counts, Wl, bl, out);
}

// Round 3
// 790.267 us; speedup vs baseline: 3.7223x; 2.2313x over previous
//
#include <hip/hip_runtime.h>

#define N_NODES 100000
#define N_EDGES 1600000
#define HID 100
#define NG 128
#define NC 8

// degi[i]=1 accounts for the self-loop; zero fill counters and pooled sums.
static __global__ void init_k(int* __restrict__ degi, int* __restrict__ fill,
                              float* __restrict__ pooled) {
  int i = blockIdx.x * blockDim.x + threadIdx.x;
  if (i < N_NODES) { degi[i] = 1; fill[i] = 0; }
  if (i < NG * HID) pooled[i] = 0.0f;
}

static __global__ void deg_k(const int* __restrict__ ei, int* __restrict__ degi) {
  int stride = gridDim.x * blockDim.x;
  for (int e = blockIdx.x * blockDim.x + threadIdx.x; e < N_EDGES; e += stride)
    atomicAdd(&degi[ei[N_EDGES + e]], 1);
}

// dinv + pre-scaled node feature xs = x*dinv (layer-1 scalar message).
static __global__ void dinv_k(const int* __restrict__ degi, const float* __restrict__ x,
                              float* __restrict__ dinv, float* __restrict__ xs) {
  int i = blockIdx.x * blockDim.x + threadIdx.x;
  if (i < N_NODES) {
    float d = 1.0f / sqrtf((float)degi[i]);
    dinv[i] = d;
    xs[i] = x[i] * d;
  }
}

// Exclusive prefix scan of in-edge counts (degi-1) -> rowptr.
#define SCAN_CHUNK 391  // ceil(100000/256)
static __global__ void scan_k(const int* __restrict__ degi, int* __restrict__ rowptr) {
  __shared__ int sums[256];
  int t = threadIdx.x;
  int lo = t * SCAN_CHUNK;
  int hi = min(lo + SCAN_CHUNK, N_NODES);
  int s = 0;
  for (int i = lo; i < hi; ++i) s += degi[i] - 1;
  sums[t] = s;
  __syncthreads();
  if (t == 0) {
    int run = 0;
    for (int i = 0; i < 256; ++i) { int v = sums[i]; sums[i] = run; run += v; }
  }
  __syncthreads();
  int run = sums[t];
  for (int i = lo; i < hi; ++i) { rowptr[i] = run; run += degi[i] - 1; }
  if (t == 255) rowptr[N_NODES] = run;  // == N_EDGES
}

static __global__ void fill_k(const int* __restrict__ ei, const int* __restrict__ rowptr,
                              int* __restrict__ fill, int* __restrict__ col) {
  int stride = gridDim.x * blockDim.x;
  for (int e = blockIdx.x * blockDim.x + threadIdx.x; e < N_EDGES; e += stride) {
    int d = ei[N_EDGES + e];
    int pos = rowptr[d] + atomicAdd(&fill[d], 1);
    col[pos] = ei[e];
  }
}

// Scalar aggregation for layer 1: sagg[n] = dinv[n]*(xs[n] + sum xs[src]).
static __global__ void sagg_k(const int* __restrict__ rowptr, const int* __restrict__ col,
                              const float* __restrict__ xs, const float* __restrict__ dinv,
                              float* __restrict__ sagg) {
  int n = blockIdx.x * blockDim.x + threadIdx.x;
  if (n >= N_NODES) return;
  float s = xs[n];
  int e0 = rowptr[n], e1 = rowptr[n + 1];
  int e = e0;
  for (; e + 4 <= e1; e += 4) {
    float v0 = xs[col[e]], v1 = xs[col[e + 1]], v2 = xs[col[e + 2]], v3 = xs[col[e + 3]];
    s += v0 + v1 + v2 + v3;
  }
  for (; e < e1; ++e) s += xs[col[e]];
  sagg[n] = s * dinv[n];
}

// Layer-1 pointwise: hs1[n,k] = dinv[n]*relu(sagg[n]*W1[k] + b1[k]); float4 lanes.
static __global__ void l1pw_k(const float* __restrict__ sagg, const float* __restrict__ W1,
                              const float* __restrict__ b1, const float* __restrict__ dinv,
                              float4* __restrict__ B4) {
  int i = blockIdx.x * blockDim.x + threadIdx.x;
  if (i >= N_NODES * 25) return;
  int n = i / 25;
  int q = i - n * 25;
  float4 w = reinterpret_cast<const float4*>(W1)[q];
  float4 b = reinterpret_cast<const float4*>(b1)[q];
  float s = sagg[n], di = dinv[n];
  float4 r;
  r.x = fmaxf(fmaf(s, w.x, b.x), 0.0f) * di;
  r.y = fmaxf(fmaf(s, w.y, b.y), 0.0f) * di;
  r.z = fmaxf(fmaf(s, w.z, b.z), 0.0f) * di;
  r.w = fmaxf(fmaf(s, w.w, b.w), 0.0f) * di;
  B4[i] = r;
}

// Pull aggregation, float4 lanes: out[n,:] = dinv[n]*(B[n,:] + sum_{src->n} B[src,:]).
// 32 lanes per node (25 active), 8 nodes per 256-thread block.
static __global__ __launch_bounds__(256) void agg4_k(
    const int* __restrict__ rowptr, const int* __restrict__ col,
    const float4* __restrict__ B4, const float* __restrict__ dinv,
    float4* __restrict__ out4) {
  int node = blockIdx.x * 8 + (threadIdx.x >> 5);
  int q = threadIdx.x & 31;
  if (node >= N_NODES || q >= 25) return;
  float4 acc = B4[node * 25 + q];  // self-loop
  int e0 = rowptr[node], e1 = rowptr[node + 1];
  int e = e0;
#pragma unroll 1
  for (; e + 2 <= e1; e += 2) {
    int s0 = col[e], s1 = col[e + 1];
    float4 v0 = B4[s0 * 25 + q];
    float4 v1 = B4[s1 * 25 + q];
    acc.x += v0.x; acc.y += v0.y; acc.z += v0.z; acc.w += v0.w;
    acc.x += v1.x; acc.y += v1.y; acc.z += v1.z; acc.w += v1.w;
  }
  if (e < e1) {
    float4 v = B4[col[e] * 25 + q];
    acc.x += v.x; acc.y += v.y; acc.z += v.z; acc.w += v.w;
  }
  float di = dinv[node];
  out4[node * 25 + q] = make_float4(acc.x * di, acc.y * di, acc.z * di, acc.w * di);
}

// Fused GEMM: Bout[n,:] = dinv[n] * relu(G[n,:] @ W + bias).
// Block = 64 nodes x 4 kc-chunks; G-tile in LDS (pad 101 -> conflict-free);
// W via wave-uniform scalar loads; acc[25]/thread.
static __global__ __launch_bounds__(256) void gemm2_k(
    const float* __restrict__ G, const float* __restrict__ W,
    const float* __restrict__ bias, const float* __restrict__ dinv,
    float* __restrict__ Bout) {
  __shared__ float tile[64 * 101];
  const int nb = blockIdx.x * 64;
#pragma unroll
  for (int i = 0; i < 25; ++i) {
    int flat = i * 256 + threadIdx.x;          // 0..6399
    int n = flat / 100, j = flat - n * 100;
    float v = 0.0f;
    if (nb + n < N_NODES) v = G[(size_t)(nb + n) * 100 + j];
    tile[n * 101 + j] = v;
  }
  __syncthreads();
  const int lane = threadIdx.x & 63;
  const int kc = threadIdx.x >> 6;             // wave-uniform
  const int n = nb + lane;
  float acc[25];
#pragma unroll
  for (int k = 0; k < 25; ++k) acc[k] = 0.0f;
  const float* trow = &tile[lane * 101];
  const float* wbase = W + kc * 25;
#pragma unroll 2
  for (int j = 0; j < 100; ++j) {
    const float hj = trow[j];
    const float* wr = wbase + j * 100;
#pragma unroll
    for (int k = 0; k < 25; ++k) acc[k] = fmaf(hj, wr[k], acc[k]);
  }
  if (n < N_NODES) {
    const float di = dinv[n];
    const int base = n * 100 + kc * 25;
#pragma unroll
    for (int k = 0; k < 25; ++k) {
      float v = fmaxf(acc[k] + bias[kc * 25 + k], 0.0f) * di;
      Bout[base + k] = v;
    }
  }
}

static __device__ int lb(const int* __restrict__ a, int n, int v) {
  int lo = 0, hi = n;
  while (lo < hi) { int m = (lo + hi) >> 1; if (a[m] < v) lo = m + 1; else hi = m; }
  return lo;
}

// Sorted-segment pool (sums + counts): 8 slices per graph, atomic per (g,slice,k).
#define PSLICES 8
static __global__ void pool2_k(const float* __restrict__ A, const int* __restrict__ batch,
                               float* __restrict__ pooled, float* __restrict__ counts) {
  int g = blockIdx.x;
  int slice = blockIdx.y;
  int k = threadIdx.x;  // 128 threads
  int lo = lb(batch, N_NODES, g);
  int hi = lb(batch, N_NODES, g + 1);
  int cnt = hi - lo;
  if (slice == 0 && k == 0) counts[g] = (float)cnt;
  int per = (cnt + PSLICES - 1) / PSLICES;
  int s0 = lo + slice * per;
  int s1 = min(s0 + per, hi);
  if (k < HID && s1 > s0) {
    float s = 0.0f;
    for (int n = s0; n < s1; ++n) s += A[n * HID + k];
    atomicAdd(&pooled[g * HID + k], s);
  }
}

// Head: t1 = mean_pooled @ W3 + b3 (per graph, in LDS), out = t1 @ Wl + bl.
static __global__ void head2_k(const float* __restrict__ pooled, const float* __restrict__ counts,
                               const float* __restrict__ W3, const float* __restrict__ b3,
                               const float* __restrict__ Wl, const float* __restrict__ bl,
                               float* __restrict__ out) {
  __shared__ float t1[HID];
  int g = blockIdx.x;
  int t = threadIdx.x;  // 128
  float inv = 1.0f / fmaxf(counts[g], 1.0f);
  if (t < HID) {
    float acc = 0.0f;
#pragma unroll 4
    for (int j = 0; j < HID; ++j)
      acc = fmaf(pooled[g * HID + j] * inv, W3[j * HID + t], acc);
    t1[t] = acc + b3[t];
  }
  __syncthreads();
  if (t < NC) {
    float acc = 0.0f;
#pragma unroll 4
    for (int j = 0; j < HID; ++j)
      acc = fmaf(t1[j], Wl[j * NC + t], acc);
    out[g * NC + t] = acc + bl[t];
  }
}

extern "C" void kernel_launch(void* const* d_in, const int* in_sizes, int n_in,
                              void* d_out, int out_size, void* d_ws, size_t ws_size,
                              hipStream_t stream) {
  const float* x    = (const float*)d_in[0];
  const int* ei     = (const int*)d_in[1];   // [2, E] flattened: src then dst
  const int* batch  = (const int*)d_in[2];
  const float* W1   = (const float*)d_in[3];
  const float* b1   = (const float*)d_in[4];
  const float* W2   = (const float*)d_in[5];
  const float* b2   = (const float*)d_in[6];
  const float* W3   = (const float*)d_in[7];
  const float* b3   = (const float*)d_in[8];
  const float* Wl   = (const float*)d_in[9];
  const float* bl   = (const float*)d_in[10];
  float* out = (float*)d_out;

  char* p = (char*)d_ws;
  auto alloc = [&](size_t bytes) {
    char* q = p;
    p += (bytes + 255) & ~(size_t)255;
    return q;
  };
  float* dinv   = (float*)alloc((size_t)N_NODES * 4);
  float* xs     = (float*)alloc((size_t)N_NODES * 4);
  float* sagg   = (float*)alloc((size_t)N_NODES * 4);
  int*   degi   = (int*)alloc((size_t)N_NODES * 4);
  int*   rowptr = (int*)alloc((size_t)(N_NODES + 1) * 4);
  int*   fill   = (int*)alloc((size_t)N_NODES * 4);
  int*   col    = (int*)alloc((size_t)N_EDGES * 4);
  float* B      = (float*)alloc((size_t)N_NODES * HID * 4);  // hs (scaled features)
  float* G      = (float*)alloc((size_t)N_NODES * HID * 4);  // agg output / M3
  float* pooled = (float*)alloc((size_t)NG * HID * 4);
  float* counts = (float*)alloc((size_t)NG * 4);

  const int T = 256;
  int gN   = (N_NODES + T - 1) / T;
  int gN25 = (N_NODES * 25 + T - 1) / T;
  int gAgg = (N_NODES + 7) / 8;
  int gGemm = (N_NODES + 63) / 64;

  init_k<<<gN, T, 0, stream>>>(degi, fill, pooled);
  deg_k<<<2048, T, 0, stream>>>(ei, degi);
  dinv_k<<<gN, T, 0, stream>>>(degi, x, dinv, xs);
  scan_k<<<1, 256, 0, stream>>>(degi, rowptr);
  fill_k<<<2048, T, 0, stream>>>(ei, rowptr, fill, col);

  // layer 1: scalar aggregation, then pointwise outer product with W1
  sagg_k<<<gN, T, 0, stream>>>(rowptr, col, xs, dinv, sagg);
  l1pw_k<<<gN25, T, 0, stream>>>(sagg, W1, b1, dinv, (float4*)B);

  // layer 2: aggregate (100-wide), then fused GEMM+bias+relu+scale
  agg4_k<<<gAgg, T, 0, stream>>>(rowptr, col, (const float4*)B, dinv, (float4*)G);
  gemm2_k<<<gGemm, T, 0, stream>>>(G, W2, b2, dinv, B);

  // layer 3: aggregate only (W3 commutes past the mean-pool)
  agg4_k<<<gAgg, T, 0, stream>>>(rowptr, col, (const float4*)B, dinv, (float4*)G);

  pool2_k<<<dim3(NG, PSLICES), 128, 0, stream>>>(G, batch, pooled, counts);
  head2_k<<<NG, 128, 0, stream>>>(pooled, counts, W3, b3, Wl, bl, out);
}

// Round 4
// 644.105 us; speedup vs baseline: 4.5669x; 1.2269x over previous
//
#include <hip/hip_runtime.h>

#define N_NODES 100000
#define N_EDGES 1600000
#define HID 100
#define NG 128
#define NC 8
#define NSCAN 391  // ceil(N_NODES / 256)

// degi[i]=1 accounts for the self-loop; zero fill counters and pooled sums.
static __global__ void init_k(int* __restrict__ degi, int* __restrict__ fill,
                              float* __restrict__ pooled) {
  int i = blockIdx.x * blockDim.x + threadIdx.x;
  if (i < N_NODES) { degi[i] = 1; fill[i] = 0; }
  if (i < NG * HID) pooled[i] = 0.0f;
}

static __global__ void deg_k(const int* __restrict__ ei, int* __restrict__ degi) {
  int stride = gridDim.x * blockDim.x;
  for (int e = blockIdx.x * blockDim.x + threadIdx.x; e < N_EDGES; e += stride)
    atomicAdd(&degi[ei[N_EDGES + e]], 1);
}

// dinv + pre-scaled node feature xs = x*dinv (layer-1 scalar message).
static __global__ void dinv_k(const int* __restrict__ degi, const float* __restrict__ x,
                              float* __restrict__ dinv, float* __restrict__ xs) {
  int i = blockIdx.x * blockDim.x + threadIdx.x;
  if (i < N_NODES) {
    float d = 1.0f / sqrtf((float)degi[i]);
    dinv[i] = d;
    xs[i] = x[i] * d;
  }
}

// --- 3-phase parallel exclusive scan of (degi-1) -> rowptr ---
static __global__ void reduce_k(const int* __restrict__ degi, int* __restrict__ bsum) {
  int i = blockIdx.x * 256 + threadIdx.x;
  int v = (i < N_NODES) ? degi[i] - 1 : 0;
#pragma unroll
  for (int d = 32; d > 0; d >>= 1) v += __shfl_down(v, d, 64);
  __shared__ int ws[4];
  if ((threadIdx.x & 63) == 0) ws[threadIdx.x >> 6] = v;
  __syncthreads();
  if (threadIdx.x == 0) bsum[blockIdx.x] = ws[0] + ws[1] + ws[2] + ws[3];
}

static __global__ void scanb_k(const int* __restrict__ bsum, int* __restrict__ bpre) {
  __shared__ int s[NSCAN];
  int t = threadIdx.x;
  for (int i = t; i < NSCAN; i += blockDim.x) s[i] = bsum[i];
  __syncthreads();
  if (t == 0) {
    int run = 0;
    for (int i = 0; i < NSCAN; ++i) { int v = s[i]; s[i] = run; run += v; }
  }
  __syncthreads();
  for (int i = t; i < NSCAN; i += blockDim.x) bpre[i] = s[i];
}

static __global__ void rowptr_k(const int* __restrict__ degi, const int* __restrict__ bpre,
                                int* __restrict__ rowptr) {
  int tid = threadIdx.x;
  int i = blockIdx.x * 256 + tid;
  int lane = tid & 63;
  int v = (i < N_NODES) ? degi[i] - 1 : 0;
  int x = v;
#pragma unroll
  for (int d = 1; d < 64; d <<= 1) {
    int t = __shfl_up(x, d, 64);
    if (lane >= d) x += t;
  }
  __shared__ int wsum[4];
  if (lane == 63) wsum[tid >> 6] = x;
  __syncthreads();
  int add = bpre[blockIdx.x];
  for (int w = 0; w < (tid >> 6); ++w) add += wsum[w];
  int incl = x + add;
  if (i < N_NODES) rowptr[i] = incl - v;  // exclusive
  if (i == N_NODES - 1) rowptr[N_NODES] = incl;
}

static __global__ void fill_k(const int* __restrict__ ei, const int* __restrict__ rowptr,
                              int* __restrict__ fill, int* __restrict__ col) {
  int stride = gridDim.x * blockDim.x;
  for (int e = blockIdx.x * blockDim.x + threadIdx.x; e < N_EDGES; e += stride) {
    int d = ei[N_EDGES + e];
    int pos = rowptr[d] + atomicAdd(&fill[d], 1);
    col[pos] = ei[e];
  }
}

// Scalar aggregation for layer 1: sagg[n] = dinv[n]*(xs[n] + sum xs[src]).
static __global__ void sagg_k(const int* __restrict__ rowptr, const int* __restrict__ col,
                              const float* __restrict__ xs, const float* __restrict__ dinv,
                              float* __restrict__ sagg) {
  int n = blockIdx.x * blockDim.x + threadIdx.x;
  if (n >= N_NODES) return;
  float s = xs[n];
  int e0 = rowptr[n], e1 = rowptr[n + 1];
  int e = e0;
  for (; e + 4 <= e1; e += 4) {
    float v0 = xs[col[e]], v1 = xs[col[e + 1]], v2 = xs[col[e + 2]], v3 = xs[col[e + 3]];
    s += v0 + v1 + v2 + v3;
  }
  for (; e < e1; ++e) s += xs[col[e]];
  sagg[n] = s * dinv[n];
}

// Layer-1 pointwise: hs1[n,k] = dinv[n]*relu(sagg[n]*W1[k] + b1[k]); float4 lanes.
static __global__ void l1pw_k(const float* __restrict__ sagg, const float* __restrict__ W1,
                              const float* __restrict__ b1, const float* __restrict__ dinv,
                              float4* __restrict__ B4) {
  int i = blockIdx.x * blockDim.x + threadIdx.x;
  if (i >= N_NODES * 25) return;
  int n = i / 25;
  int q = i - n * 25;
  float4 w = reinterpret_cast<const float4*>(W1)[q];
  float4 b = reinterpret_cast<const float4*>(b1)[q];
  float s = sagg[n], di = dinv[n];
  float4 r;
  r.x = fmaxf(fmaf(s, w.x, b.x), 0.0f) * di;
  r.y = fmaxf(fmaf(s, w.y, b.y), 0.0f) * di;
  r.z = fmaxf(fmaf(s, w.z, b.z), 0.0f) * di;
  r.w = fmaxf(fmaf(s, w.w, b.w), 0.0f) * di;
  B4[i] = r;
}

// Pull aggregation, float4 lanes: out[n,:] = dinv[n]*(B[n,:] + sum_{src->n} B[src,:]).
// 32 lanes per node (25 active), 8 nodes per 256-thread block, 4-deep MLP unroll.
static __global__ __launch_bounds__(256) void agg4_k(
    const int* __restrict__ rowptr, const int* __restrict__ col,
    const float4* __restrict__ B4, const float* __restrict__ dinv,
    float4* __restrict__ out4) {
  int node = blockIdx.x * 8 + (threadIdx.x >> 5);
  int q = threadIdx.x & 31;
  if (node >= N_NODES || q >= 25) return;
  float4 acc = B4[node * 25 + q];  // self-loop
  int e0 = rowptr[node], e1 = rowptr[node + 1];
  int e = e0;
#pragma unroll 1
  for (; e + 4 <= e1; e += 4) {
    int s0 = col[e], s1 = col[e + 1], s2 = col[e + 2], s3 = col[e + 3];
    float4 v0 = B4[s0 * 25 + q];
    float4 v1 = B4[s1 * 25 + q];
    float4 v2 = B4[s2 * 25 + q];
    float4 v3 = B4[s3 * 25 + q];
    acc.x += v0.x + v1.x + v2.x + v3.x;
    acc.y += v0.y + v1.y + v2.y + v3.y;
    acc.z += v0.z + v1.z + v2.z + v3.z;
    acc.w += v0.w + v1.w + v2.w + v3.w;
  }
  for (; e < e1; ++e) {
    float4 v = B4[col[e] * 25 + q];
    acc.x += v.x; acc.y += v.y; acc.z += v.z; acc.w += v.w;
  }
  float di = dinv[node];
  out4[node * 25 + q] = make_float4(acc.x * di, acc.y * di, acc.z * di, acc.w * di);
}

// Fused GEMM: Bout[n,:] = dinv[n] * relu(G[n,:] @ W + bias).
static __global__ __launch_bounds__(256) void gemm2_k(
    const float* __restrict__ G, const float* __restrict__ W,
    const float* __restrict__ bias, const float* __restrict__ dinv,
    float* __restrict__ Bout) {
  __shared__ float tile[64 * 101];
  const int nb = blockIdx.x * 64;
#pragma unroll
  for (int i = 0; i < 25; ++i) {
    int flat = i * 256 + threadIdx.x;          // 0..6399
    int n = flat / 100, j = flat - n * 100;
    float v = 0.0f;
    if (nb + n < N_NODES) v = G[(size_t)(nb + n) * 100 + j];
    tile[n * 101 + j] = v;
  }
  __syncthreads();
  const int lane = threadIdx.x & 63;
  const int kc = threadIdx.x >> 6;             // wave-uniform
  const int n = nb + lane;
  float acc[25];
#pragma unroll
  for (int k = 0; k < 25; ++k) acc[k] = 0.0f;
  const float* trow = &tile[lane * 101];
  const float* wbase = W + kc * 25;
#pragma unroll 2
  for (int j = 0; j < 100; ++j) {
    const float hj = trow[j];
    const float* wr = wbase + j * 100;
#pragma unroll
    for (int k = 0; k < 25; ++k) acc[k] = fmaf(hj, wr[k], acc[k]);
  }
  if (n < N_NODES) {
    const float di = dinv[n];
    const int base = n * 100 + kc * 25;
#pragma unroll
    for (int k = 0; k < 25; ++k) {
      float v = fmaxf(acc[k] + bias[kc * 25 + k], 0.0f) * di;
      Bout[base + k] = v;
    }
  }
}

static __device__ int lb(const int* __restrict__ a, int n, int v) {
  int lo = 0, hi = n;
  while (lo < hi) { int m = (lo + hi) >> 1; if (a[m] < v) lo = m + 1; else hi = m; }
  return lo;
}

// Sorted-segment pool (sums + counts): 8 slices per graph, atomic per (g,slice,k).
#define PSLICES 8
static __global__ void pool2_k(const float* __restrict__ A, const int* __restrict__ batch,
                               float* __restrict__ pooled, float* __restrict__ counts) {
  int g = blockIdx.x;
  int slice = blockIdx.y;
  int k = threadIdx.x;  // 128 threads
  int lo = lb(batch, N_NODES, g);
  int hi = lb(batch, N_NODES, g + 1);
  int cnt = hi - lo;
  if (slice == 0 && k == 0) counts[g] = (float)cnt;
  int per = (cnt + PSLICES - 1) / PSLICES;
  int s0 = lo + slice * per;
  int s1 = min(s0 + per, hi);
  if (k < HID && s1 > s0) {
    float s = 0.0f;
    for (int n = s0; n < s1; ++n) s += A[n * HID + k];
    atomicAdd(&pooled[g * HID + k], s);
  }
}

// Head: t1 = mean_pooled @ W3 + b3 (per graph, in LDS), out = t1 @ Wl + bl.
static __global__ void head2_k(const float* __restrict__ pooled, const float* __restrict__ counts,
                               const float* __restrict__ W3, const float* __restrict__ b3,
                               const float* __restrict__ Wl, const float* __restrict__ bl,
                               float* __restrict__ out) {
  __shared__ float t1[HID];
  int g = blockIdx.x;
  int t = threadIdx.x;  // 128
  float inv = 1.0f / fmaxf(counts[g], 1.0f);
  if (t < HID) {
    float acc = 0.0f;
#pragma unroll 4
    for (int j = 0; j < HID; ++j)
      acc = fmaf(pooled[g * HID + j] * inv, W3[j * HID + t], acc);
    t1[t] = acc + b3[t];
  }
  __syncthreads();
  if (t < NC) {
    float acc = 0.0f;
#pragma unroll 4
    for (int j = 0; j < HID; ++j)
      acc = fmaf(t1[j], Wl[j * NC + t], acc);
    out[g * NC + t] = acc + bl[t];
  }
}

extern "C" void kernel_launch(void* const* d_in, const int* in_sizes, int n_in,
                              void* d_out, int out_size, void* d_ws, size_t ws_size,
                              hipStream_t stream) {
  const float* x    = (const float*)d_in[0];
  const int* ei     = (const int*)d_in[1];   // [2, E] flattened: src then dst
  const int* batch  = (const int*)d_in[2];
  const float* W1   = (const float*)d_in[3];
  const float* b1   = (const float*)d_in[4];
  const float* W2   = (const float*)d_in[5];
  const float* b2   = (const float*)d_in[6];
  const float* W3   = (const float*)d_in[7];
  const float* b3   = (const float*)d_in[8];
  const float* Wl   = (const float*)d_in[9];
  const float* bl   = (const float*)d_in[10];
  float* out = (float*)d_out;

  char* p = (char*)d_ws;
  auto alloc = [&](size_t bytes) {
    char* q = p;
    p += (bytes + 255) & ~(size_t)255;
    return q;
  };
  float* dinv   = (float*)alloc((size_t)N_NODES * 4);
  float* xs     = (float*)alloc((size_t)N_NODES * 4);
  float* sagg   = (float*)alloc((size_t)N_NODES * 4);
  int*   degi   = (int*)alloc((size_t)N_NODES * 4);
  int*   rowptr = (int*)alloc((size_t)(N_NODES + 1) * 4);
  int*   fill   = (int*)alloc((size_t)N_NODES * 4);
  int*   bsum   = (int*)alloc((size_t)NSCAN * 4);
  int*   bpre   = (int*)alloc((size_t)NSCAN * 4);
  int*   col    = (int*)alloc((size_t)N_EDGES * 4);
  float* B      = (float*)alloc((size_t)N_NODES * HID * 4);  // hs (scaled features)
  float* G      = (float*)alloc((size_t)N_NODES * HID * 4);  // agg output / M3
  float* pooled = (float*)alloc((size_t)NG * HID * 4);
  float* counts = (float*)alloc((size_t)NG * 4);

  const int T = 256;
  int gN   = (N_NODES + T - 1) / T;
  int gN25 = (N_NODES * 25 + T - 1) / T;
  int gAgg = (N_NODES + 7) / 8;
  int gGemm = (N_NODES + 63) / 64;

  init_k<<<gN, T, 0, stream>>>(degi, fill, pooled);
  deg_k<<<2048, T, 0, stream>>>(ei, degi);
  dinv_k<<<gN, T, 0, stream>>>(degi, x, dinv, xs);
  reduce_k<<<NSCAN, 256, 0, stream>>>(degi, bsum);
  scanb_k<<<1, 256, 0, stream>>>(bsum, bpre);
  rowptr_k<<<NSCAN, 256, 0, stream>>>(degi, bpre, rowptr);
  fill_k<<<2048, T, 0, stream>>>(ei, rowptr, fill, col);

  // layer 1: scalar aggregation, then pointwise outer product with W1
  sagg_k<<<gN, T, 0, stream>>>(rowptr, col, xs, dinv, sagg);
  l1pw_k<<<gN25, T, 0, stream>>>(sagg, W1, b1, dinv, (float4*)B);

  // layer 2: aggregate (100-wide), then fused GEMM+bias+relu+scale
  agg4_k<<<gAgg, T, 0, stream>>>(rowptr, col, (const float4*)B, dinv, (float4*)G);
  gemm2_k<<<gGemm, T, 0, stream>>>(G, W2, b2, dinv, B);

  // layer 3: aggregate only (W3 commutes past the mean-pool)
  agg4_k<<<gAgg, T, 0, stream>>>(rowptr, col, (const float4*)B, dinv, (float4*)G);

  pool2_k<<<dim3(NG, PSLICES), 128, 0, stream>>>(G, batch, pooled, counts);
  head2_k<<<NG, 128, 0, stream>>>(pooled, counts, W3, b3, Wl, bl, out);
}

// Round 5
// 549.426 us; speedup vs baseline: 5.3539x; 1.1723x over previous
//
#include <hip/hip_runtime.h>

#define N_NODES 100000
#define N_EDGES 1600000
#define HID 100
#define NG 128
#define NC 8
#define NSCAN 391  // ceil(N_NODES / 256)

// degi[i]=1 accounts for the self-loop; zero fill counters and pooled sums.
static __global__ void init_k(int* __restrict__ degi, int* __restrict__ fill,
                              float* __restrict__ pooled) {
  int i = blockIdx.x * blockDim.x + threadIdx.x;
  if (i < N_NODES) { degi[i] = 1; fill[i] = 0; }
  if (i < NG * HID) pooled[i] = 0.0f;
}

static __global__ void deg_k(const int* __restrict__ ei, int* __restrict__ degi) {
  int stride = gridDim.x * blockDim.x;
  for (int e = blockIdx.x * blockDim.x + threadIdx.x; e < N_EDGES; e += stride)
    atomicAdd(&degi[ei[N_EDGES + e]], 1);
}

// dinv + pre-scaled node feature xs = x*dinv (layer-1 scalar message).
static __global__ void dinv_k(const int* __restrict__ degi, const float* __restrict__ x,
                              float* __restrict__ dinv, float* __restrict__ xs) {
  int i = blockIdx.x * blockDim.x + threadIdx.x;
  if (i < N_NODES) {
    float d = 1.0f / sqrtf((float)degi[i]);
    dinv[i] = d;
    xs[i] = x[i] * d;
  }
}

// --- 3-phase parallel exclusive scan of (degi-1) -> rowptr ---
static __global__ void reduce_k(const int* __restrict__ degi, int* __restrict__ bsum) {
  int i = blockIdx.x * 256 + threadIdx.x;
  int v = (i < N_NODES) ? degi[i] - 1 : 0;
#pragma unroll
  for (int d = 32; d > 0; d >>= 1) v += __shfl_down(v, d, 64);
  __shared__ int ws[4];
  if ((threadIdx.x & 63) == 0) ws[threadIdx.x >> 6] = v;
  __syncthreads();
  if (threadIdx.x == 0) bsum[blockIdx.x] = ws[0] + ws[1] + ws[2] + ws[3];
}

static __global__ void scanb_k(const int* __restrict__ bsum, int* __restrict__ bpre) {
  __shared__ int s[NSCAN];
  int t = threadIdx.x;
  for (int i = t; i < NSCAN; i += blockDim.x) s[i] = bsum[i];
  __syncthreads();
  if (t == 0) {
    int run = 0;
    for (int i = 0; i < NSCAN; ++i) { int v = s[i]; s[i] = run; run += v; }
  }
  __syncthreads();
  for (int i = t; i < NSCAN; i += blockDim.x) bpre[i] = s[i];
}

static __global__ void rowptr_k(const int* __restrict__ degi, const int* __restrict__ bpre,
                                int* __restrict__ rowptr) {
  int tid = threadIdx.x;
  int i = blockIdx.x * 256 + tid;
  int lane = tid & 63;
  int v = (i < N_NODES) ? degi[i] - 1 : 0;
  int x = v;
#pragma unroll
  for (int d = 1; d < 64; d <<= 1) {
    int t = __shfl_up(x, d, 64);
    if (lane >= d) x += t;
  }
  __shared__ int wsum[4];
  if (lane == 63) wsum[tid >> 6] = x;
  __syncthreads();
  int add = bpre[blockIdx.x];
  for (int w = 0; w < (tid >> 6); ++w) add += wsum[w];
  int incl = x + add;
  if (i < N_NODES) rowptr[i] = incl - v;  // exclusive
  if (i == N_NODES - 1) rowptr[N_NODES] = incl;
}

static __global__ void fill_k(const int* __restrict__ ei, const int* __restrict__ rowptr,
                              int* __restrict__ fill, int* __restrict__ col) {
  int stride = gridDim.x * blockDim.x;
  for (int e = blockIdx.x * blockDim.x + threadIdx.x; e < N_EDGES; e += stride) {
    int d = ei[N_EDGES + e];
    int pos = rowptr[d] + atomicAdd(&fill[d], 1);
    col[pos] = ei[e];
  }
}

// Scalar aggregation for layer 1: sagg[n] = dinv[n]*(xs[n] + sum xs[src]).
static __global__ void sagg_k(const int* __restrict__ rowptr, const int* __restrict__ col,
                              const float* __restrict__ xs, const float* __restrict__ dinv,
                              float* __restrict__ sagg) {
  int n = blockIdx.x * blockDim.x + threadIdx.x;
  if (n >= N_NODES) return;
  float s = xs[n];
  int e0 = rowptr[n], e1 = rowptr[n + 1];
  int e = e0;
  for (; e + 4 <= e1; e += 4) {
    float v0 = xs[col[e]], v1 = xs[col[e + 1]], v2 = xs[col[e + 2]], v3 = xs[col[e + 3]];
    s += v0 + v1 + v2 + v3;
  }
  for (; e < e1; ++e) s += xs[col[e]];
  sagg[n] = s * dinv[n];
}

// Layer-1 pointwise: hs1[n,k] = dinv[n]*relu(sagg[n]*W1[k] + b1[k]); float4 lanes.
static __global__ void l1pw_k(const float* __restrict__ sagg, const float* __restrict__ W1,
                              const float* __restrict__ b1, const float* __restrict__ dinv,
                              float4* __restrict__ B4) {
  int i = blockIdx.x * blockDim.x + threadIdx.x;
  if (i >= N_NODES * 25) return;
  int n = i / 25;
  int q = i - n * 25;
  float4 w = reinterpret_cast<const float4*>(W1)[q];
  float4 b = reinterpret_cast<const float4*>(b1)[q];
  float s = sagg[n], di = dinv[n];
  float4 r;
  r.x = fmaxf(fmaf(s, w.x, b.x), 0.0f) * di;
  r.y = fmaxf(fmaf(s, w.y, b.y), 0.0f) * di;
  r.z = fmaxf(fmaf(s, w.z, b.z), 0.0f) * di;
  r.w = fmaxf(fmaf(s, w.w, b.w), 0.0f) * di;
  B4[i] = r;
}

// Pull aggregation, float4 lanes: out[n,:] = dinv[n]*(B[n,:] + sum_{src->n} B[src,:]).
// 32 lanes per node (25 active), 8 nodes per 256-thread block, 4-deep MLP unroll.
static __global__ __launch_bounds__(256) void agg4_k(
    const int* __restrict__ rowptr, const int* __restrict__ col,
    const float4* __restrict__ B4, const float* __restrict__ dinv,
    float4* __restrict__ out4) {
  int node = blockIdx.x * 8 + (threadIdx.x >> 5);
  int q = threadIdx.x & 31;
  if (node >= N_NODES || q >= 25) return;
  float4 acc = B4[node * 25 + q];  // self-loop
  int e0 = rowptr[node], e1 = rowptr[node + 1];
  int e = e0;
#pragma unroll 1
  for (; e + 4 <= e1; e += 4) {
    int s0 = col[e], s1 = col[e + 1], s2 = col[e + 2], s3 = col[e + 3];
    float4 v0 = B4[s0 * 25 + q];
    float4 v1 = B4[s1 * 25 + q];
    float4 v2 = B4[s2 * 25 + q];
    float4 v3 = B4[s3 * 25 + q];
    acc.x += v0.x + v1.x + v2.x + v3.x;
    acc.y += v0.y + v1.y + v2.y + v3.y;
    acc.z += v0.z + v1.z + v2.z + v3.z;
    acc.w += v0.w + v1.w + v2.w + v3.w;
  }
  for (; e < e1; ++e) {
    float4 v = B4[col[e] * 25 + q];
    acc.x += v.x; acc.y += v.y; acc.z += v.z; acc.w += v.w;
  }
  float di = dinv[node];
  out4[node * 25 + q] = make_float4(acc.x * di, acc.y * di, acc.z * di, acc.w * di);
}

// Fused GEMM: Bout[n,:] = dinv[n] * relu(G[n,:] @ W + bias).
// Block = 64 nodes x 4 kc-chunks; G-tile in LDS (pad 101 -> conflict-free);
// W forced to SCALAR loads (readfirstlane-uniform base -> s_load into SGPRs,
// SMEM pipe), FMAs are v_fmac v,s,v. acc[25]/thread.
static __global__ __launch_bounds__(256) void gemm2_k(
    const float* __restrict__ G, const float* __restrict__ W,
    const float* __restrict__ bias, const float* __restrict__ dinv,
    float* __restrict__ Bout) {
  __shared__ float tile[64 * 101];
  const int nb = blockIdx.x * 64;
#pragma unroll
  for (int i = 0; i < 25; ++i) {
    int flat = i * 256 + threadIdx.x;          // 0..6399
    int n = flat / 100, j = flat - n * 100;
    float v = 0.0f;
    if (nb + n < N_NODES) v = G[(size_t)(nb + n) * 100 + j];
    tile[n * 101 + j] = v;
  }
  __syncthreads();
  const int lane = threadIdx.x & 63;
  const int kc = __builtin_amdgcn_readfirstlane(threadIdx.x >> 6);  // force wave-uniform
  const int n = nb + lane;
  float acc[25];
#pragma unroll
  for (int k = 0; k < 25; ++k) acc[k] = 0.0f;
  const float* trow = &tile[lane * 101];
  const float* wbase = W + kc * 25;            // uniform pointer
#pragma unroll 4
  for (int j = 0; j < 100; ++j) {
    float wv[25];
    const float* wr = wbase + j * 100;         // uniform address -> s_load
#pragma unroll
    for (int k = 0; k < 25; ++k) wv[k] = wr[k];
    const float hj = trow[j];
#pragma unroll
    for (int k = 0; k < 25; ++k) acc[k] = fmaf(hj, wv[k], acc[k]);
  }
  if (n < N_NODES) {
    const float di = dinv[n];
    const int base = n * 100 + kc * 25;
#pragma unroll
    for (int k = 0; k < 25; ++k) {
      float v = fmaxf(acc[k] + bias[kc * 25 + k], 0.0f) * di;
      Bout[base + k] = v;
    }
  }
}

static __device__ int lb(const int* __restrict__ a, int n, int v) {
  int lo = 0, hi = n;
  while (lo < hi) { int m = (lo + hi) >> 1; if (a[m] < v) lo = m + 1; else hi = m; }
  return lo;
}

// Sorted-segment pool (sums + counts): 8 slices per graph, atomic per (g,slice,k).
#define PSLICES 8
static __global__ void pool2_k(const float* __restrict__ A, const int* __restrict__ batch,
                               float* __restrict__ pooled, float* __restrict__ counts) {
  int g = blockIdx.x;
  int slice = blockIdx.y;
  int k = threadIdx.x;  // 128 threads
  int lo = lb(batch, N_NODES, g);
  int hi = lb(batch, N_NODES, g + 1);
  int cnt = hi - lo;
  if (slice == 0 && k == 0) counts[g] = (float)cnt;
  int per = (cnt + PSLICES - 1) / PSLICES;
  int s0 = lo + slice * per;
  int s1 = min(s0 + per, hi);
  if (k < HID && s1 > s0) {
    float s = 0.0f;
    for (int n = s0; n < s1; ++n) s += A[n * HID + k];
    atomicAdd(&pooled[g * HID + k], s);
  }
}

// Head: t1 = mean_pooled @ W3 + b3 (per graph, in LDS), out = t1 @ Wl + bl.
static __global__ void head2_k(const float* __restrict__ pooled, const float* __restrict__ counts,
                               const float* __restrict__ W3, const float* __restrict__ b3,
                               const float* __restrict__ Wl, const float* __restrict__ bl,
                               float* __restrict__ out) {
  __shared__ float t1[HID];
  int g = blockIdx.x;
  int t = threadIdx.x;  // 128
  float inv = 1.0f / fmaxf(counts[g], 1.0f);
  if (t < HID) {
    float acc = 0.0f;
#pragma unroll 4
    for (int j = 0; j < HID; ++j)
      acc = fmaf(pooled[g * HID + j] * inv, W3[j * HID + t], acc);
    t1[t] = acc + b3[t];
  }
  __syncthreads();
  if (t < NC) {
    float acc = 0.0f;
#pragma unroll 4
    for (int j = 0; j < HID; ++j)
      acc = fmaf(t1[j], Wl[j * NC + t], acc);
    out[g * NC + t] = acc + bl[t];
  }
}

extern "C" void kernel_launch(void* const* d_in, const int* in_sizes, int n_in,
                              void* d_out, int out_size, void* d_ws, size_t ws_size,
                              hipStream_t stream) {
  const float* x    = (const float*)d_in[0];
  const int* ei     = (const int*)d_in[1];   // [2, E] flattened: src then dst
  const int* batch  = (const int*)d_in[2];
  const float* W1   = (const float*)d_in[3];
  const float* b1   = (const float*)d_in[4];
  const float* W2   = (const float*)d_in[5];
  const float* b2   = (const float*)d_in[6];
  const float* W3   = (const float*)d_in[7];
  const float* b3   = (const float*)d_in[8];
  const float* Wl   = (const float*)d_in[9];
  const float* bl   = (const float*)d_in[10];
  float* out = (float*)d_out;

  char* p = (char*)d_ws;
  auto alloc = [&](size_t bytes) {
    char* q = p;
    p += (bytes + 255) & ~(size_t)255;
    return q;
  };
  float* dinv   = (float*)alloc((size_t)N_NODES * 4);
  float* xs     = (float*)alloc((size_t)N_NODES * 4);
  float* sagg   = (float*)alloc((size_t)N_NODES * 4);
  int*   degi   = (int*)alloc((size_t)N_NODES * 4);
  int*   rowptr = (int*)alloc((size_t)(N_NODES + 1) * 4);
  int*   fill   = (int*)alloc((size_t)N_NODES * 4);
  int*   bsum   = (int*)alloc((size_t)NSCAN * 4);
  int*   bpre   = (int*)alloc((size_t)NSCAN * 4);
  int*   col    = (int*)alloc((size_t)N_EDGES * 4);
  float* B      = (float*)alloc((size_t)N_NODES * HID * 4);  // hs (scaled features)
  float* G      = (float*)alloc((size_t)N_NODES * HID * 4);  // agg output / M3
  float* pooled = (float*)alloc((size_t)NG * HID * 4);
  float* counts = (float*)alloc((size_t)NG * 4);

  const int T = 256;
  int gN   = (N_NODES + T - 1) / T;
  int gN25 = (N_NODES * 25 + T - 1) / T;
  int gAgg = (N_NODES + 7) / 8;
  int gGemm = (N_NODES + 63) / 64;

  init_k<<<gN, T, 0, stream>>>(degi, fill, pooled);
  deg_k<<<2048, T, 0, stream>>>(ei, degi);
  dinv_k<<<gN, T, 0, stream>>>(degi, x, dinv, xs);
  reduce_k<<<NSCAN, 256, 0, stream>>>(degi, bsum);
  scanb_k<<<1, 256, 0, stream>>>(bsum, bpre);
  rowptr_k<<<NSCAN, 256, 0, stream>>>(degi, bpre, rowptr);
  fill_k<<<2048, T, 0, stream>>>(ei, rowptr, fill, col);

  // layer 1: scalar aggregation, then pointwise outer product with W1
  sagg_k<<<gN, T, 0, stream>>>(rowptr, col, xs, dinv, sagg);
  l1pw_k<<<gN25, T, 0, stream>>>(sagg, W1, b1, dinv, (float4*)B);

  // layer 2: aggregate (100-wide), then fused GEMM+bias+relu+scale
  agg4_k<<<gAgg, T, 0, stream>>>(rowptr, col, (const float4*)B, dinv, (float4*)G);
  gemm2_k<<<gGemm, T, 0, stream>>>(G, W2, b2, dinv, B);

  // layer 3: aggregate only (W3 commutes past the mean-pool)
  agg4_k<<<gAgg, T, 0, stream>>>(rowptr, col, (const float4*)B, dinv, (float4*)G);

  pool2_k<<<dim3(NG, PSLICES), 128, 0, stream>>>(G, batch, pooled, counts);
  head2_k<<<NG, 128, 0, stream>>>(pooled, counts, W3, b3, Wl, bl, out);
}

// Round 6
// 512.692 us; speedup vs baseline: 5.7375x; 1.0716x over previous
//
#include <hip/hip_runtime.h>

#define N_NODES 100000
#define N_EDGES 1600000
#define HID 100
#define NG 128
#define NC 8
#define NSCAN 391  // ceil(N_NODES / 256)
#define XCD 8
#define SLICE_NODES 12500  // N_NODES / XCD

// degi[i]=1 accounts for the self-loop; zero pooled sums.
static __global__ void init_k(int* __restrict__ degi, float* __restrict__ pooled) {
  int i = blockIdx.x * blockDim.x + threadIdx.x;
  if (i < N_NODES) degi[i] = 1;
  if (i < NG * HID) pooled[i] = 0.0f;
}

// Degree count, XCD-sliced: blocks with the same (blockIdx&7) land on the same
// XCD (observed round-robin; perf heuristic only). Each slice-group streams the
// full dst array coalesced but only atomics its own 12.5K-node window ->
// L2-local RMW, no cross-XCD line ping-pong.
static __global__ void deg_k(const int* __restrict__ ei, int* __restrict__ degi) {
  int slice = blockIdx.x & (XCD - 1);
  int lo = slice * SLICE_NODES;
  int hi = min(lo + SLICE_NODES, N_NODES);
  int bid = blockIdx.x >> 3;
  int stride = (gridDim.x >> 3) * blockDim.x;
  for (int e = bid * blockDim.x + threadIdx.x; e < N_EDGES; e += stride) {
    int d = ei[N_EDGES + e];
    if (d >= lo && d < hi) atomicAdd(&degi[d], 1);
  }
}

// dinv + pre-scaled node feature xs = x*dinv (layer-1 scalar message).
static __global__ void dinv_k(const int* __restrict__ degi, const float* __restrict__ x,
                              float* __restrict__ dinv, float* __restrict__ xs) {
  int i = blockIdx.x * blockDim.x + threadIdx.x;
  if (i < N_NODES) {
    float d = 1.0f / sqrtf((float)degi[i]);
    dinv[i] = d;
    xs[i] = x[i] * d;
  }
}

// --- 3-phase parallel exclusive scan of (degi-1) -> rowptr (+cursor copy) ---
static __global__ void reduce_k(const int* __restrict__ degi, int* __restrict__ bsum) {
  int i = blockIdx.x * 256 + threadIdx.x;
  int v = (i < N_NODES) ? degi[i] - 1 : 0;
#pragma unroll
  for (int d = 32; d > 0; d >>= 1) v += __shfl_down(v, d, 64);
  __shared__ int ws[4];
  if ((threadIdx.x & 63) == 0) ws[threadIdx.x >> 6] = v;
  __syncthreads();
  if (threadIdx.x == 0) bsum[blockIdx.x] = ws[0] + ws[1] + ws[2] + ws[3];
}

static __global__ void scanb_k(const int* __restrict__ bsum, int* __restrict__ bpre) {
  __shared__ int s[NSCAN];
  int t = threadIdx.x;
  for (int i = t; i < NSCAN; i += blockDim.x) s[i] = bsum[i];
  __syncthreads();
  if (t == 0) {
    int run = 0;
    for (int i = 0; i < NSCAN; ++i) { int v = s[i]; s[i] = run; run += v; }
  }
  __syncthreads();
  for (int i = t; i < NSCAN; i += blockDim.x) bpre[i] = s[i];
}

static __global__ void rowptr_k(const int* __restrict__ degi, const int* __restrict__ bpre,
                                int* __restrict__ rowptr, int* __restrict__ cursor) {
  int tid = threadIdx.x;
  int i = blockIdx.x * 256 + tid;
  int lane = tid & 63;
  int v = (i < N_NODES) ? degi[i] - 1 : 0;
  int x = v;
#pragma unroll
  for (int d = 1; d < 64; d <<= 1) {
    int t = __shfl_up(x, d, 64);
    if (lane >= d) x += t;
  }
  __shared__ int wsum[4];
  if (lane == 63) wsum[tid >> 6] = x;
  __syncthreads();
  int add = bpre[blockIdx.x];
  for (int w = 0; w < (tid >> 6); ++w) add += wsum[w];
  int incl = x + add;
  if (i < N_NODES) {
    int excl = incl - v;
    rowptr[i] = excl;
    cursor[i] = excl;  // fill cursor starts at row base
  }
  if (i == N_NODES - 1) rowptr[N_NODES] = incl;
}

// CSR fill, XCD-sliced like deg_k: single atomic cursor bump per edge; col
// writes land in the slice's private ~800KB window (L2-local writebacks).
static __global__ void fill_k(const int* __restrict__ ei, int* __restrict__ cursor,
                              int* __restrict__ col) {
  int slice = blockIdx.x & (XCD - 1);
  int lo = slice * SLICE_NODES;
  int hi = min(lo + SLICE_NODES, N_NODES);
  int bid = blockIdx.x >> 3;
  int stride = (gridDim.x >> 3) * blockDim.x;
  for (int e = bid * blockDim.x + threadIdx.x; e < N_EDGES; e += stride) {
    int s = ei[e];             // unconditional: keep the src stream coalesced
    int d = ei[N_EDGES + e];
    if (d >= lo && d < hi) {
      int pos = atomicAdd(&cursor[d], 1);
      col[pos] = s;
    }
  }
}

// Scalar aggregation for layer 1: sagg[n] = dinv[n]*(xs[n] + sum xs[src]).
static __global__ void sagg_k(const int* __restrict__ rowptr, const int* __restrict__ col,
                              const float* __restrict__ xs, const float* __restrict__ dinv,
                              float* __restrict__ sagg) {
  int n = blockIdx.x * blockDim.x + threadIdx.x;
  if (n >= N_NODES) return;
  float s = xs[n];
  int e0 = rowptr[n], e1 = rowptr[n + 1];
  int e = e0;
  for (; e + 4 <= e1; e += 4) {
    float v0 = xs[col[e]], v1 = xs[col[e + 1]], v2 = xs[col[e + 2]], v3 = xs[col[e + 3]];
    s += v0 + v1 + v2 + v3;
  }
  for (; e < e1; ++e) s += xs[col[e]];
  sagg[n] = s * dinv[n];
}

// Layer-1 pointwise: hs1[n,k] = dinv[n]*relu(sagg[n]*W1[k] + b1[k]); float4 lanes.
static __global__ void l1pw_k(const float* __restrict__ sagg, const float* __restrict__ W1,
                              const float* __restrict__ b1, const float* __restrict__ dinv,
                              float4* __restrict__ B4) {
  int i = blockIdx.x * blockDim.x + threadIdx.x;
  if (i >= N_NODES * 25) return;
  int n = i / 25;
  int q = i - n * 25;
  float4 w = reinterpret_cast<const float4*>(W1)[q];
  float4 b = reinterpret_cast<const float4*>(b1)[q];
  float s = sagg[n], di = dinv[n];
  float4 r;
  r.x = fmaxf(fmaf(s, w.x, b.x), 0.0f) * di;
  r.y = fmaxf(fmaf(s, w.y, b.y), 0.0f) * di;
  r.z = fmaxf(fmaf(s, w.z, b.z), 0.0f) * di;
  r.w = fmaxf(fmaf(s, w.w, b.w), 0.0f) * di;
  B4[i] = r;
}

// Pull aggregation, float4 lanes: out[n,:] = dinv[n]*(B[n,:] + sum_{src->n} B[src,:]).
// 32 lanes per node (25 active), 8 nodes per 256-thread block, 4-deep MLP unroll.
static __global__ __launch_bounds__(256) void agg4_k(
    const int* __restrict__ rowptr, const int* __restrict__ col,
    const float4* __restrict__ B4, const float* __restrict__ dinv,
    float4* __restrict__ out4) {
  int node = blockIdx.x * 8 + (threadIdx.x >> 5);
  int q = threadIdx.x & 31;
  if (node >= N_NODES || q >= 25) return;
  float4 acc = B4[node * 25 + q];  // self-loop
  int e0 = rowptr[node], e1 = rowptr[node + 1];
  int e = e0;
#pragma unroll 1
  for (; e + 4 <= e1; e += 4) {
    int s0 = col[e], s1 = col[e + 1], s2 = col[e + 2], s3 = col[e + 3];
    float4 v0 = B4[s0 * 25 + q];
    float4 v1 = B4[s1 * 25 + q];
    float4 v2 = B4[s2 * 25 + q];
    float4 v3 = B4[s3 * 25 + q];
    acc.x += v0.x + v1.x + v2.x + v3.x;
    acc.y += v0.y + v1.y + v2.y + v3.y;
    acc.z += v0.z + v1.z + v2.z + v3.z;
    acc.w += v0.w + v1.w + v2.w + v3.w;
  }
  for (; e < e1; ++e) {
    float4 v = B4[col[e] * 25 + q];
    acc.x += v.x; acc.y += v.y; acc.z += v.z; acc.w += v.w;
  }
  float di = dinv[node];
  out4[node * 25 + q] = make_float4(acc.x * di, acc.y * di, acc.z * di, acc.w * di);
}

// Fused GEMM: Bout[n,:] = dinv[n] * relu(G[n,:] @ W + bias).
// W forced to SCALAR loads (readfirstlane-uniform base -> s_load, SMEM pipe).
static __global__ __launch_bounds__(256) void gemm2_k(
    const float* __restrict__ G, const float* __restrict__ W,
    const float* __restrict__ bias, const float* __restrict__ dinv,
    float* __restrict__ Bout) {
  __shared__ float tile[64 * 101];
  const int nb = blockIdx.x * 64;
#pragma unroll
  for (int i = 0; i < 25; ++i) {
    int flat = i * 256 + threadIdx.x;          // 0..6399
    int n = flat / 100, j = flat - n * 100;
    float v = 0.0f;
    if (nb + n < N_NODES) v = G[(size_t)(nb + n) * 100 + j];
    tile[n * 101 + j] = v;
  }
  __syncthreads();
  const int lane = threadIdx.x & 63;
  const int kc = __builtin_amdgcn_readfirstlane(threadIdx.x >> 6);  // wave-uniform
  const int n = nb + lane;
  float acc[25];
#pragma unroll
  for (int k = 0; k < 25; ++k) acc[k] = 0.0f;
  const float* trow = &tile[lane * 101];
  const float* wbase = W + kc * 25;            // uniform pointer
#pragma unroll 4
  for (int j = 0; j < 100; ++j) {
    float wv[25];
    const float* wr = wbase + j * 100;         // uniform address -> s_load
#pragma unroll
    for (int k = 0; k < 25; ++k) wv[k] = wr[k];
    const float hj = trow[j];
#pragma unroll
    for (int k = 0; k < 25; ++k) acc[k] = fmaf(hj, wv[k], acc[k]);
  }
  if (n < N_NODES) {
    const float di = dinv[n];
    const int base = n * 100 + kc * 25;
#pragma unroll
    for (int k = 0; k < 25; ++k) {
      float v = fmaxf(acc[k] + bias[kc * 25 + k], 0.0f) * di;
      Bout[base + k] = v;
    }
  }
}

static __device__ int lb(const int* __restrict__ a, int n, int v) {
  int lo = 0, hi = n;
  while (lo < hi) { int m = (lo + hi) >> 1; if (a[m] < v) lo = m + 1; else hi = m; }
  return lo;
}

// Sorted-segment pool (sums + counts): 8 slices per graph, atomic per (g,slice,k).
#define PSLICES 8
static __global__ void pool2_k(const float* __restrict__ A, const int* __restrict__ batch,
                               float* __restrict__ pooled, float* __restrict__ counts) {
  int g = blockIdx.x;
  int slice = blockIdx.y;
  int k = threadIdx.x;  // 128 threads
  int lo = lb(batch, N_NODES, g);
  int hi = lb(batch, N_NODES, g + 1);
  int cnt = hi - lo;
  if (slice == 0 && k == 0) counts[g] = (float)cnt;
  int per = (cnt + PSLICES - 1) / PSLICES;
  int s0 = lo + slice * per;
  int s1 = min(s0 + per, hi);
  if (k < HID && s1 > s0) {
    float s = 0.0f;
    for (int n = s0; n < s1; ++n) s += A[n * HID + k];
    atomicAdd(&pooled[g * HID + k], s);
  }
}

// Head: t1 = mean_pooled @ W3 + b3 (per graph, in LDS), out = t1 @ Wl + bl.
static __global__ void head2_k(const float* __restrict__ pooled, const float* __restrict__ counts,
                               const float* __restrict__ W3, const float* __restrict__ b3,
                               const float* __restrict__ Wl, const float* __restrict__ bl,
                               float* __restrict__ out) {
  __shared__ float t1[HID];
  int g = blockIdx.x;
  int t = threadIdx.x;  // 128
  float inv = 1.0f / fmaxf(counts[g], 1.0f);
  if (t < HID) {
    float acc = 0.0f;
#pragma unroll 4
    for (int j = 0; j < HID; ++j)
      acc = fmaf(pooled[g * HID + j] * inv, W3[j * HID + t], acc);
    t1[t] = acc + b3[t];
  }
  __syncthreads();
  if (t < NC) {
    float acc = 0.0f;
#pragma unroll 4
    for (int j = 0; j < HID; ++j)
      acc = fmaf(t1[j], Wl[j * NC + t], acc);
    out[g * NC + t] = acc + bl[t];
  }
}

extern "C" void kernel_launch(void* const* d_in, const int* in_sizes, int n_in,
                              void* d_out, int out_size, void* d_ws, size_t ws_size,
                              hipStream_t stream) {
  const float* x    = (const float*)d_in[0];
  const int* ei     = (const int*)d_in[1];   // [2, E] flattened: src then dst
  const int* batch  = (const int*)d_in[2];
  const float* W1   = (const float*)d_in[3];
  const float* b1   = (const float*)d_in[4];
  const float* W2   = (const float*)d_in[5];
  const float* b2   = (const float*)d_in[6];
  const float* W3   = (const float*)d_in[7];
  const float* b3   = (const float*)d_in[8];
  const float* Wl   = (const float*)d_in[9];
  const float* bl   = (const float*)d_in[10];
  float* out = (float*)d_out;

  char* p = (char*)d_ws;
  auto alloc = [&](size_t bytes) {
    char* q = p;
    p += (bytes + 255) & ~(size_t)255;
    return q;
  };
  float* dinv   = (float*)alloc((size_t)N_NODES * 4);
  float* xs     = (float*)alloc((size_t)N_NODES * 4);
  float* sagg   = (float*)alloc((size_t)N_NODES * 4);
  int*   degi   = (int*)alloc((size_t)N_NODES * 4);
  int*   rowptr = (int*)alloc((size_t)(N_NODES + 1) * 4);
  int*   cursor = (int*)alloc((size_t)N_NODES * 4);
  int*   bsum   = (int*)alloc((size_t)NSCAN * 4);
  int*   bpre   = (int*)alloc((size_t)NSCAN * 4);
  int*   col    = (int*)alloc((size_t)N_EDGES * 4);
  float* B      = (float*)alloc((size_t)N_NODES * HID * 4);  // hs (scaled features)
  float* G      = (float*)alloc((size_t)N_NODES * HID * 4);  // agg output / M3
  float* pooled = (float*)alloc((size_t)NG * HID * 4);
  float* counts = (float*)alloc((size_t)NG * 4);

  const int T = 256;
  int gN   = (N_NODES + T - 1) / T;
  int gN25 = (N_NODES * 25 + T - 1) / T;
  int gAgg = (N_NODES + 7) / 8;
  int gGemm = (N_NODES + 63) / 64;

  init_k<<<gN, T, 0, stream>>>(degi, pooled);
  deg_k<<<2048, T, 0, stream>>>(ei, degi);
  dinv_k<<<gN, T, 0, stream>>>(degi, x, dinv, xs);
  reduce_k<<<NSCAN, 256, 0, stream>>>(degi, bsum);
  scanb_k<<<1, 256, 0, stream>>>(bsum, bpre);
  rowptr_k<<<NSCAN, 256, 0, stream>>>(degi, bpre, rowptr, cursor);
  fill_k<<<2048, T, 0, stream>>>(ei, cursor, col);

  // layer 1: scalar aggregation, then pointwise outer product with W1
  sagg_k<<<gN, T, 0, stream>>>(rowptr, col, xs, dinv, sagg);
  l1pw_k<<<gN25, T, 0, stream>>>(sagg, W1, b1, dinv, (float4*)B);

  // layer 2: aggregate (100-wide), then fused GEMM+bias+relu+scale
  agg4_k<<<gAgg, T, 0, stream>>>(rowptr, col, (const float4*)B, dinv, (float4*)G);
  gemm2_k<<<gGemm, T, 0, stream>>>(G, W2, b2, dinv, B);

  // layer 3: aggregate only (W3 commutes past the mean-pool)
  agg4_k<<<gAgg, T, 0, stream>>>(rowptr, col, (const float4*)B, dinv, (float4*)G);

  pool2_k<<<dim3(NG, PSLICES), 128, 0, stream>>>(G, batch, pooled, counts);
  head2_k<<<NG, 128, 0, stream>>>(pooled, counts, W3, b3, Wl, bl, out);
}

// Round 7
// 442.937 us; speedup vs baseline: 6.6411x; 1.1575x over previous
//
#include <hip/hip_runtime.h>

#define N_NODES 100000
#define N_EDGES 1600000
#define HID 100
#define NG 128
#define NC 8
#define NSCAN 391  // ceil(N_NODES / 256)
#define XCD 8
#define SLICE_NODES 12500  // N_NODES / XCD

// degi[i]=1 accounts for the self-loop; zero pooled sums.
static __global__ void init_k(int* __restrict__ degi, float* __restrict__ pooled) {
  int i = blockIdx.x * blockDim.x + threadIdx.x;
  if (i < N_NODES) degi[i] = 1;
  if (i < NG * HID) pooled[i] = 0.0f;
}

// Degree count, XCD-sliced (blocks with same blockIdx&7 -> same XCD; perf
// heuristic only): stream dst coalesced, atomic only own 12.5K-node window.
static __global__ void deg_k(const int* __restrict__ ei, int* __restrict__ degi) {
  int slice = blockIdx.x & (XCD - 1);
  int lo = slice * SLICE_NODES;
  int hi = min(lo + SLICE_NODES, N_NODES);
  int bid = blockIdx.x >> 3;
  int stride = (gridDim.x >> 3) * blockDim.x;
  for (int e = bid * blockDim.x + threadIdx.x; e < N_EDGES; e += stride) {
    int d = ei[N_EDGES + e];
    if (d >= lo && d < hi) atomicAdd(&degi[d], 1);
  }
}

// dinv + pre-scaled node feature xs = x*dinv (layer-1 scalar message).
static __global__ void dinv_k(const int* __restrict__ degi, const float* __restrict__ x,
                              float* __restrict__ dinv, float* __restrict__ xs) {
  int i = blockIdx.x * blockDim.x + threadIdx.x;
  if (i < N_NODES) {
    float d = 1.0f / sqrtf((float)degi[i]);
    dinv[i] = d;
    xs[i] = x[i] * d;
  }
}

// --- 3-phase parallel exclusive scan of (degi-1) -> rowptr (+cursor copy) ---
static __global__ void reduce_k(const int* __restrict__ degi, int* __restrict__ bsum) {
  int i = blockIdx.x * 256 + threadIdx.x;
  int v = (i < N_NODES) ? degi[i] - 1 : 0;
#pragma unroll
  for (int d = 32; d > 0; d >>= 1) v += __shfl_down(v, d, 64);
  __shared__ int ws[4];
  if ((threadIdx.x & 63) == 0) ws[threadIdx.x >> 6] = v;
  __syncthreads();
  if (threadIdx.x == 0) bsum[blockIdx.x] = ws[0] + ws[1] + ws[2] + ws[3];
}

static __global__ void scanb_k(const int* __restrict__ bsum, int* __restrict__ bpre) {
  __shared__ int s[NSCAN];
  int t = threadIdx.x;
  for (int i = t; i < NSCAN; i += blockDim.x) s[i] = bsum[i];
  __syncthreads();
  if (t == 0) {
    int run = 0;
    for (int i = 0; i < NSCAN; ++i) { int v = s[i]; s[i] = run; run += v; }
  }
  __syncthreads();
  for (int i = t; i < NSCAN; i += blockDim.x) bpre[i] = s[i];
}

static __global__ void rowptr_k(const int* __restrict__ degi, const int* __restrict__ bpre,
                                int* __restrict__ rowptr, int* __restrict__ cursor) {
  int tid = threadIdx.x;
  int i = blockIdx.x * 256 + tid;
  int lane = tid & 63;
  int v = (i < N_NODES) ? degi[i] - 1 : 0;
  int x = v;
#pragma unroll
  for (int d = 1; d < 64; d <<= 1) {
    int t = __shfl_up(x, d, 64);
    if (lane >= d) x += t;
  }
  __shared__ int wsum[4];
  if (lane == 63) wsum[tid >> 6] = x;
  __syncthreads();
  int add = bpre[blockIdx.x];
  for (int w = 0; w < (tid >> 6); ++w) add += wsum[w];
  int incl = x + add;
  if (i < N_NODES) {
    int excl = incl - v;
    rowptr[i] = excl;
    cursor[i] = excl;  // fill cursor starts at row base
  }
  if (i == N_NODES - 1) rowptr[N_NODES] = incl;
}

// CSR fill, XCD-sliced: one atomic cursor bump per edge; col writes land in the
// slice's private ~800KB window (L2-local writebacks).
static __global__ void fill_k(const int* __restrict__ ei, int* __restrict__ cursor,
                              int* __restrict__ col) {
  int slice = blockIdx.x & (XCD - 1);
  int lo = slice * SLICE_NODES;
  int hi = min(lo + SLICE_NODES, N_NODES);
  int bid = blockIdx.x >> 3;
  int stride = (gridDim.x >> 3) * blockDim.x;
  for (int e = bid * blockDim.x + threadIdx.x; e < N_EDGES; e += stride) {
    int s = ei[e];             // unconditional: keep the src stream coalesced
    int d = ei[N_EDGES + e];
    if (d >= lo && d < hi) {
      int pos = atomicAdd(&cursor[d], 1);
      col[pos] = s;
    }
  }
}

// Layer-1 scalar aggregation -> packed pair (sagg, dinv) per node.
// sagg[n] = dinv[n]*(xs[n] + sum xs[src]).
static __global__ void sagg_k(const int* __restrict__ rowptr, const int* __restrict__ col,
                              const float* __restrict__ xs, const float* __restrict__ dinv,
                              float2* __restrict__ pairs) {
  int n = blockIdx.x * blockDim.x + threadIdx.x;
  if (n >= N_NODES) return;
  float s = xs[n];
  int e0 = rowptr[n], e1 = rowptr[n + 1];
  int e = e0;
  for (; e + 4 <= e1; e += 4) {
    float v0 = xs[col[e]], v1 = xs[col[e + 1]], v2 = xs[col[e + 2]], v3 = xs[col[e + 3]];
    s += v0 + v1 + v2 + v3;
  }
  for (; e < e1; ++e) s += xs[col[e]];
  float di = dinv[n];
  pairs[n] = make_float2(s * di, di);
}

// Fused layer-1-materialize + layer-2-aggregate:
//   G[n,k] = dinv_n * sum_{i in {n} u N(n)} dinv_i * relu(sagg_i*W1_k + b1_k)
// Gathers only the 8B pair per edge (800KB array -> L2-resident) and
// recomputes the rank-1 relu row on the fly. 32 lanes/node (25 active,
// lane q owns k-quad q), 8 nodes per 256-thread block.
static __global__ __launch_bounds__(256) void l12_k(
    const int* __restrict__ rowptr, const int* __restrict__ col,
    const float2* __restrict__ pairs, const float* __restrict__ W1,
    const float* __restrict__ b1, float4* __restrict__ G4) {
  int node = blockIdx.x * 8 + (threadIdx.x >> 5);
  int q = threadIdx.x & 31;
  if (node >= N_NODES || q >= 25) return;
  float4 w = reinterpret_cast<const float4*>(W1)[q];
  float4 b = reinterpret_cast<const float4*>(b1)[q];
  float2 self = pairs[node];
  float4 acc;
  acc.x = self.y * fmaxf(fmaf(self.x, w.x, b.x), 0.0f);
  acc.y = self.y * fmaxf(fmaf(self.x, w.y, b.y), 0.0f);
  acc.z = self.y * fmaxf(fmaf(self.x, w.z, b.z), 0.0f);
  acc.w = self.y * fmaxf(fmaf(self.x, w.w, b.w), 0.0f);
  int e0 = rowptr[node], e1 = rowptr[node + 1];
  int e = e0;
#pragma unroll 1
  for (; e + 4 <= e1; e += 4) {
    float2 p0 = pairs[col[e]];
    float2 p1 = pairs[col[e + 1]];
    float2 p2 = pairs[col[e + 2]];
    float2 p3 = pairs[col[e + 3]];
    acc.x = fmaf(p0.y, fmaxf(fmaf(p0.x, w.x, b.x), 0.0f), acc.x);
    acc.y = fmaf(p0.y, fmaxf(fmaf(p0.x, w.y, b.y), 0.0f), acc.y);
    acc.z = fmaf(p0.y, fmaxf(fmaf(p0.x, w.z, b.z), 0.0f), acc.z);
    acc.w = fmaf(p0.y, fmaxf(fmaf(p0.x, w.w, b.w), 0.0f), acc.w);
    acc.x = fmaf(p1.y, fmaxf(fmaf(p1.x, w.x, b.x), 0.0f), acc.x);
    acc.y = fmaf(p1.y, fmaxf(fmaf(p1.x, w.y, b.y), 0.0f), acc.y);
    acc.z = fmaf(p1.y, fmaxf(fmaf(p1.x, w.z, b.z), 0.0f), acc.z);
    acc.w = fmaf(p1.y, fmaxf(fmaf(p1.x, w.w, b.w), 0.0f), acc.w);
    acc.x = fmaf(p2.y, fmaxf(fmaf(p2.x, w.x, b.x), 0.0f), acc.x);
    acc.y = fmaf(p2.y, fmaxf(fmaf(p2.x, w.y, b.y), 0.0f), acc.y);
    acc.z = fmaf(p2.y, fmaxf(fmaf(p2.x, w.z, b.z), 0.0f), acc.z);
    acc.w = fmaf(p2.y, fmaxf(fmaf(p2.x, w.w, b.w), 0.0f), acc.w);
    acc.x = fmaf(p3.y, fmaxf(fmaf(p3.x, w.x, b.x), 0.0f), acc.x);
    acc.y = fmaf(p3.y, fmaxf(fmaf(p3.x, w.y, b.y), 0.0f), acc.y);
    acc.z = fmaf(p3.y, fmaxf(fmaf(p3.x, w.z, b.z), 0.0f), acc.z);
    acc.w = fmaf(p3.y, fmaxf(fmaf(p3.x, w.w, b.w), 0.0f), acc.w);
  }
  for (; e < e1; ++e) {
    float2 p = pairs[col[e]];
    acc.x = fmaf(p.y, fmaxf(fmaf(p.x, w.x, b.x), 0.0f), acc.x);
    acc.y = fmaf(p.y, fmaxf(fmaf(p.x, w.y, b.y), 0.0f), acc.y);
    acc.z = fmaf(p.y, fmaxf(fmaf(p.x, w.z, b.z), 0.0f), acc.z);
    acc.w = fmaf(p.y, fmaxf(fmaf(p.x, w.w, b.w), 0.0f), acc.w);
  }
  float di = self.y;
  G4[node * 25 + q] = make_float4(acc.x * di, acc.y * di, acc.z * di, acc.w * di);
}

// Pull aggregation, float4 lanes: out[n,:] = dinv[n]*(B[n,:] + sum_{src->n} B[src,:]).
static __global__ __launch_bounds__(256) void agg4_k(
    const int* __restrict__ rowptr, const int* __restrict__ col,
    const float4* __restrict__ B4, const float* __restrict__ dinv,
    float4* __restrict__ out4) {
  int node = blockIdx.x * 8 + (threadIdx.x >> 5);
  int q = threadIdx.x & 31;
  if (node >= N_NODES || q >= 25) return;
  float4 acc = B4[node * 25 + q];  // self-loop
  int e0 = rowptr[node], e1 = rowptr[node + 1];
  int e = e0;
#pragma unroll 1
  for (; e + 4 <= e1; e += 4) {
    int s0 = col[e], s1 = col[e + 1], s2 = col[e + 2], s3 = col[e + 3];
    float4 v0 = B4[s0 * 25 + q];
    float4 v1 = B4[s1 * 25 + q];
    float4 v2 = B4[s2 * 25 + q];
    float4 v3 = B4[s3 * 25 + q];
    acc.x += v0.x + v1.x + v2.x + v3.x;
    acc.y += v0.y + v1.y + v2.y + v3.y;
    acc.z += v0.z + v1.z + v2.z + v3.z;
    acc.w += v0.w + v1.w + v2.w + v3.w;
  }
  for (; e < e1; ++e) {
    float4 v = B4[col[e] * 25 + q];
    acc.x += v.x; acc.y += v.y; acc.z += v.z; acc.w += v.w;
  }
  float di = dinv[node];
  out4[node * 25 + q] = make_float4(acc.x * di, acc.y * di, acc.z * di, acc.w * di);
}

// Fused GEMM: Bout[n,:] = dinv[n] * relu(G[n,:] @ W + bias).
// W forced to SCALAR loads (readfirstlane-uniform base -> s_load, SMEM pipe).
static __global__ __launch_bounds__(256) void gemm2_k(
    const float* __restrict__ G, const float* __restrict__ W,
    const float* __restrict__ bias, const float* __restrict__ dinv,
    float* __restrict__ Bout) {
  __shared__ float tile[64 * 101];
  const int nb = blockIdx.x * 64;
#pragma unroll
  for (int i = 0; i < 25; ++i) {
    int flat = i * 256 + threadIdx.x;          // 0..6399
    int n = flat / 100, j = flat - n * 100;
    float v = 0.0f;
    if (nb + n < N_NODES) v = G[(size_t)(nb + n) * 100 + j];
    tile[n * 101 + j] = v;
  }
  __syncthreads();
  const int lane = threadIdx.x & 63;
  const int kc = __builtin_amdgcn_readfirstlane(threadIdx.x >> 6);  // wave-uniform
  const int n = nb + lane;
  float acc[25];
#pragma unroll
  for (int k = 0; k < 25; ++k) acc[k] = 0.0f;
  const float* trow = &tile[lane * 101];
  const float* wbase = W + kc * 25;            // uniform pointer
#pragma unroll 4
  for (int j = 0; j < 100; ++j) {
    float wv[25];
    const float* wr = wbase + j * 100;         // uniform address -> s_load
#pragma unroll
    for (int k = 0; k < 25; ++k) wv[k] = wr[k];
    const float hj = trow[j];
#pragma unroll
    for (int k = 0; k < 25; ++k) acc[k] = fmaf(hj, wv[k], acc[k]);
  }
  if (n < N_NODES) {
    const float di = dinv[n];
    const int base = n * 100 + kc * 25;
#pragma unroll
    for (int k = 0; k < 25; ++k) {
      float v = fmaxf(acc[k] + bias[kc * 25 + k], 0.0f) * di;
      Bout[base + k] = v;
    }
  }
}

static __device__ int lb(const int* __restrict__ a, int n, int v) {
  int lo = 0, hi = n;
  while (lo < hi) { int m = (lo + hi) >> 1; if (a[m] < v) lo = m + 1; else hi = m; }
  return lo;
}

// Sorted-segment pool (sums + counts): 8 slices per graph, atomic per (g,slice,k).
#define PSLICES 8
static __global__ void pool2_k(const float* __restrict__ A, const int* __restrict__ batch,
                               float* __restrict__ pooled, float* __restrict__ counts) {
  int g = blockIdx.x;
  int slice = blockIdx.y;
  int k = threadIdx.x;  // 128 threads
  int lo = lb(batch, N_NODES, g);
  int hi = lb(batch, N_NODES, g + 1);
  int cnt = hi - lo;
  if (slice == 0 && k == 0) counts[g] = (float)cnt;
  int per = (cnt + PSLICES - 1) / PSLICES;
  int s0 = lo + slice * per;
  int s1 = min(s0 + per, hi);
  if (k < HID && s1 > s0) {
    float s = 0.0f;
    for (int n = s0; n < s1; ++n) s += A[n * HID + k];
    atomicAdd(&pooled[g * HID + k], s);
  }
}

// Head: t1 = mean_pooled @ W3 + b3 (per graph, in LDS), out = t1 @ Wl + bl.
static __global__ void head2_k(const float* __restrict__ pooled, const float* __restrict__ counts,
                               const float* __restrict__ W3, const float* __restrict__ b3,
                               const float* __restrict__ Wl, const float* __restrict__ bl,
                               float* __restrict__ out) {
  __shared__ float t1[HID];
  int g = blockIdx.x;
  int t = threadIdx.x;  // 128
  float inv = 1.0f / fmaxf(counts[g], 1.0f);
  if (t < HID) {
    float acc = 0.0f;
#pragma unroll 4
    for (int j = 0; j < HID; ++j)
      acc = fmaf(pooled[g * HID + j] * inv, W3[j * HID + t], acc);
    t1[t] = acc + b3[t];
  }
  __syncthreads();
  if (t < NC) {
    float acc = 0.0f;
#pragma unroll 4
    for (int j = 0; j < HID; ++j)
      acc = fmaf(t1[j], Wl[j * NC + t], acc);
    out[g * NC + t] = acc + bl[t];
  }
}

extern "C" void kernel_launch(void* const* d_in, const int* in_sizes, int n_in,
                              void* d_out, int out_size, void* d_ws, size_t ws_size,
                              hipStream_t stream) {
  const float* x    = (const float*)d_in[0];
  const int* ei     = (const int*)d_in[1];   // [2, E] flattened: src then dst
  const int* batch  = (const int*)d_in[2];
  const float* W1   = (const float*)d_in[3];
  const float* b1   = (const float*)d_in[4];
  const float* W2   = (const float*)d_in[5];
  const float* b2   = (const float*)d_in[6];
  const float* W3   = (const float*)d_in[7];
  const float* b3   = (const float*)d_in[8];
  const float* Wl   = (const float*)d_in[9];
  const float* bl   = (const float*)d_in[10];
  float* out = (float*)d_out;

  char* p = (char*)d_ws;
  auto alloc = [&](size_t bytes) {
    char* q = p;
    p += (bytes + 255) & ~(size_t)255;
    return q;
  };
  float* dinv   = (float*)alloc((size_t)N_NODES * 4);
  float* xs     = (float*)alloc((size_t)N_NODES * 4);
  float2* pairs = (float2*)alloc((size_t)N_NODES * 8);
  int*   degi   = (int*)alloc((size_t)N_NODES * 4);
  int*   rowptr = (int*)alloc((size_t)(N_NODES + 1) * 4);
  int*   cursor = (int*)alloc((size_t)N_NODES * 4);
  int*   bsum   = (int*)alloc((size_t)NSCAN * 4);
  int*   bpre   = (int*)alloc((size_t)NSCAN * 4);
  int*   col    = (int*)alloc((size_t)N_EDGES * 4);
  float* B      = (float*)alloc((size_t)N_NODES * HID * 4);  // hs2 (scaled H2)
  float* G      = (float*)alloc((size_t)N_NODES * HID * 4);  // agg output / M3
  float* pooled = (float*)alloc((size_t)NG * HID * 4);
  float* counts = (float*)alloc((size_t)NG * 4);

  const int T = 256;
  int gN   = (N_NODES + T - 1) / T;
  int gAgg = (N_NODES + 7) / 8;
  int gGemm = (N_NODES + 63) / 64;

  init_k<<<gN, T, 0, stream>>>(degi, pooled);
  deg_k<<<2048, T, 0, stream>>>(ei, degi);
  dinv_k<<<gN, T, 0, stream>>>(degi, x, dinv, xs);
  reduce_k<<<NSCAN, 256, 0, stream>>>(degi, bsum);
  scanb_k<<<1, 256, 0, stream>>>(bsum, bpre);
  rowptr_k<<<NSCAN, 256, 0, stream>>>(degi, bpre, rowptr, cursor);
  fill_k<<<2048, T, 0, stream>>>(ei, cursor, col);

  // layer 1: scalar aggregation -> (sagg, dinv) pairs
  sagg_k<<<gN, T, 0, stream>>>(rowptr, col, xs, dinv, pairs);

  // layer 2: fused layer-1-materialize + aggregate (8B/edge gather), then GEMM
  l12_k<<<gAgg, T, 0, stream>>>(rowptr, col, pairs, W1, b1, (float4*)G);
  gemm2_k<<<gGemm, T, 0, stream>>>(G, W2, b2, dinv, B);

  // layer 3: aggregate only (W3 commutes past the mean-pool)
  agg4_k<<<gAgg, T, 0, stream>>>(rowptr, col, (const float4*)B, dinv, (float4*)G);

  pool2_k<<<dim3(NG, PSLICES), 128, 0, stream>>>(G, batch, pooled, counts);
  head2_k<<<NG, 128, 0, stream>>>(pooled, counts, W3, b3, Wl, bl, out);
}